// Round 1
// baseline (100.520 us; speedup 1.0000x reference)
//
#include <hip/hip_runtime.h>

// MeanAggregator: out[b, :] = (1/K) * sum_{k<K} features[idx[b,k], :]
// B=16384 rows, K=15 neighbors, U=19997 feature rows, D=256 fp32.
//
// Layout: one 64-lane wave per output row; each lane owns one float4
// (64 lanes * 16B = 1024B = full D=256 row). Block = 256 threads = 4 rows.
// Indices are pre-loaded into registers so the 15 gather loads issue
// back-to-back (ILP latency hiding); idx loads are wave-uniform-address
// broadcasts (cheap).

#define K_NEIGH 15
#define D_VEC4 64   // D/4

__global__ __launch_bounds__(256) void MeanAggregator_46024869544579_kernel(
    const int* __restrict__ idx,      // [B, K]
    const float4* __restrict__ feat,  // [U, D/4]
    float4* __restrict__ out,         // [B, D/4]
    int B) {
  const int row = blockIdx.x * 4 + (threadIdx.x >> 6);
  const int lane = threadIdx.x & 63;
  if (row >= B) return;

  const int* rowidx = idx + (size_t)row * K_NEIGH;

  // Pre-load all K indices (wave-uniform addresses -> broadcast loads).
  int j[K_NEIGH];
#pragma unroll
  for (int k = 0; k < K_NEIGH; ++k) j[k] = rowidx[k];

  // Issue all K gather loads, then accumulate.
  float4 v[K_NEIGH];
#pragma unroll
  for (int k = 0; k < K_NEIGH; ++k) {
    v[k] = feat[(size_t)j[k] * D_VEC4 + lane];
  }

  float4 acc;
  acc.x = 0.f; acc.y = 0.f; acc.z = 0.f; acc.w = 0.f;
#pragma unroll
  for (int k = 0; k < K_NEIGH; ++k) {
    acc.x += v[k].x;
    acc.y += v[k].y;
    acc.z += v[k].z;
    acc.w += v[k].w;
  }

  const float s = 1.0f / (float)K_NEIGH;
  acc.x *= s; acc.y *= s; acc.z *= s; acc.w *= s;

  out[(size_t)row * D_VEC4 + lane] = acc;
}

extern "C" void kernel_launch(void* const* d_in, const int* in_sizes, int n_in,
                              void* d_out, int out_size, void* d_ws, size_t ws_size,
                              hipStream_t stream) {
  const int* idx = (const int*)d_in[0];          // [B, K] int32
  const float4* feat = (const float4*)d_in[1];   // [U, D/4]
  float4* out = (float4*)d_out;                  // [B, D/4]

  const int B = in_sizes[0] / K_NEIGH;           // 16384
  const int rows_per_block = 4;                  // 256 threads / 64 lanes
  const int grid = (B + rows_per_block - 1) / rows_per_block;

  MeanAggregator_46024869544579_kernel<<<grid, 256, 0, stream>>>(idx, feat, out, B);
}

// Round 2
// 91.243 us; speedup vs baseline: 1.1017x; 1.1017x over previous
//
#include <hip/hip_runtime.h>
#include <hip/hip_fp16.h>

// MeanAggregator: out[b,:] = (1/K) * sum_k features[idx[b,k],:]
// B=16384, K=15, U=19997, D=256 fp32.
//
// R1 analysis: fp32 gather (252 MB, 8x128B lines/row) ran at ~2.7 TB/s
// effective == ~4 B/cyc/CU — per-CU outstanding-miss limited (table > L2/XCD,
// ~900cyc miss latency). Fix: quantize features to fp16 in d_ws (pre-pass),
// halving gathered lines (512B/row) and v[] register pressure. Accumulate fp32.
// Threshold is 2.9e-2 (bf16-grade); fp16 adds <=~3e-3 absmax.

#define K_NEIGH 15
#define D 256
#define DV 64   // uint2 (4 halves) per feature row

__global__ __launch_bounds__(256) void cvt_f32_to_f16(
    const float4* __restrict__ src,  // [U*D/4]
    uint2* __restrict__ dst,         // [U*D/4] (4 halves each)
    int n4) {
  int i = blockIdx.x * 256 + threadIdx.x;
  if (i >= n4) return;
  float4 v = src[i];
  __half2 a = __floats2half2_rn(v.x, v.y);
  __half2 b = __floats2half2_rn(v.z, v.w);
  uint2 p;
  p.x = *reinterpret_cast<unsigned int*>(&a);
  p.y = *reinterpret_cast<unsigned int*>(&b);
  dst[i] = p;
}

__global__ __launch_bounds__(256) void MeanAggregator_46024869544579_kernel(
    const int* __restrict__ idx,     // [B, K]
    const uint2* __restrict__ feat,  // [U, DV] fp16x4 packed
    float4* __restrict__ out,        // [B, D/4]
    int B) {
  const int row = blockIdx.x * 4 + (threadIdx.x >> 6);
  const int lane = threadIdx.x & 63;
  if (row >= B) return;

  const int* rowidx = idx + (size_t)row * K_NEIGH;

  int j[K_NEIGH];
#pragma unroll
  for (int k = 0; k < K_NEIGH; ++k) j[k] = rowidx[k];

  // All 15 gather loads in flight (8 B/lane, 512 B/wave, 4x128B lines/row).
  uint2 v[K_NEIGH];
#pragma unroll
  for (int k = 0; k < K_NEIGH; ++k) {
    v[k] = feat[(size_t)j[k] * DV + lane];
  }

  float ax = 0.f, ay = 0.f, az = 0.f, aw = 0.f;
#pragma unroll
  for (int k = 0; k < K_NEIGH; ++k) {
    __half2 h0 = *reinterpret_cast<__half2*>(&v[k].x);
    __half2 h1 = *reinterpret_cast<__half2*>(&v[k].y);
    float2 f0 = __half22float2(h0);
    float2 f1 = __half22float2(h1);
    ax += f0.x; ay += f0.y; az += f1.x; aw += f1.y;
  }

  const float s = 1.0f / (float)K_NEIGH;
  float4 r;
  r.x = ax * s; r.y = ay * s; r.z = az * s; r.w = aw * s;
  out[(size_t)row * DV + lane] = r;
}

extern "C" void kernel_launch(void* const* d_in, const int* in_sizes, int n_in,
                              void* d_out, int out_size, void* d_ws, size_t ws_size,
                              hipStream_t stream) {
  const int* idx = (const int*)d_in[0];        // [B, K] int32
  const float4* feat32 = (const float4*)d_in[1];
  float4* out = (float4*)d_out;

  const int B = in_sizes[0] / K_NEIGH;         // 16384
  const int n4 = in_sizes[1] / 4;              // U*D/4 = 1,279,808

  uint2* feat16 = (uint2*)d_ws;                // 10.25 MB in workspace

  // Pass 1: fp32 -> fp16 feature table (streaming, ~5 us).
  const int cvt_grid = (n4 + 255) / 256;
  cvt_f32_to_f16<<<cvt_grid, 256, 0, stream>>>(feat32, feat16, n4);

  // Pass 2: gather-mean. One wave per row, 4 rows per 256-thread block.
  const int grid = (B + 3) / 4;
  MeanAggregator_46024869544579_kernel<<<grid, 256, 0, stream>>>(idx, feat16, out, B);
}

// Round 3
// 90.394 us; speedup vs baseline: 1.1120x; 1.0094x over previous
//
#include <hip/hip_runtime.h>
#include <hip/hip_fp16.h>

// MeanAggregator: out[b,:] = (1/K) * sum_k features[idx[b,k],:]
// B=16384, K=15, U=19997, D=256 fp32.
//
// R2 post-mortem: time fits ~70% per-gather-INSTRUCTION, ~30% per-line.
// 245,760 divergent wave-gathers is the wall (~2.8 G instr/s device-wide).
// R3: fp16 table + dwordx4 so ONE instruction gathers TWO neighbor rows
// (lanes 0-31 -> row j[2t], lanes 32-63 -> row j[2t+1]): 15 -> 8 gather
// instructions per output row. Cross-half reduce via __shfl_xor(.,32).

#define K_NEIGH 15
#define D 256
#define ROW_U4 32   // uint4 (8 halves, 16B) per fp16 feature row

// fp32 -> fp16 table conversion: 8 floats per thread (2x float4 in, 1x uint4 out)
__global__ __launch_bounds__(256) void cvt_f32_to_f16(
    const float4* __restrict__ src,  // [U*D/4]
    uint4* __restrict__ dst,         // [U*D/8]
    int n8) {
  int i = blockIdx.x * 256 + threadIdx.x;
  if (i >= n8) return;
  float4 v0 = src[2 * i];
  float4 v1 = src[2 * i + 1];
  __half2 a = __floats2half2_rn(v0.x, v0.y);
  __half2 b = __floats2half2_rn(v0.z, v0.w);
  __half2 c = __floats2half2_rn(v1.x, v1.y);
  __half2 d = __floats2half2_rn(v1.z, v1.w);
  uint4 p;
  p.x = *reinterpret_cast<unsigned int*>(&a);
  p.y = *reinterpret_cast<unsigned int*>(&b);
  p.z = *reinterpret_cast<unsigned int*>(&c);
  p.w = *reinterpret_cast<unsigned int*>(&d);
  dst[i] = p;
}

__global__ __launch_bounds__(256) void MeanAggregator_46024869544579_kernel(
    const int* __restrict__ idx,     // [B, K]
    const uint4* __restrict__ feat,  // [U, ROW_U4] fp16x8 packed
    float4* __restrict__ out,        // [B, D/4]
    int B) {
  const int lane = threadIdx.x & 63;
  const int row = blockIdx.x * 4 + (threadIdx.x >> 6);
  const int half = lane >> 5;   // 0: even k, 1: odd k
  const int sub = lane & 31;    // 16B chunk within a feature row
  if (row >= B) return;

  const int* rowidx = idx + (size_t)row * K_NEIGH;
  int j[K_NEIGH];
#pragma unroll
  for (int k = 0; k < K_NEIGH; ++k) j[k] = rowidx[k];

  // 8 gather instructions, each fetching 2 neighbor rows (one per 32-lane half).
  // t=7 half=1 is a dummy (re-loads j[14]); its contribution is zero-weighted.
  uint4 v[8];
#pragma unroll
  for (int t = 0; t < 8; ++t) {
    const int k1 = (2 * t + 1 < K_NEIGH) ? (2 * t + 1) : (K_NEIGH - 1);
    const int jj = half ? j[k1] : j[2 * t];
    v[t] = feat[(size_t)jj * ROW_U4 + sub];
  }

  float acc[8];
#pragma unroll
  for (int i = 0; i < 8; ++i) acc[i] = 0.f;

  const float w7 = half ? 0.f : 1.f;
#pragma unroll
  for (int t = 0; t < 8; ++t) {
    const unsigned int* pv = &v[t].x;
    const float w = (t == 7) ? w7 : 1.f;
#pragma unroll
    for (int q = 0; q < 4; ++q) {
      __half2 h = *reinterpret_cast<const __half2*>(&pv[q]);
      float2 f = __half22float2(h);
      acc[2 * q] += w * f.x;
      acc[2 * q + 1] += w * f.y;
    }
  }

  // Cross-half reduction: even-k partials (half 0) + odd-k partials (half 1).
#pragma unroll
  for (int i = 0; i < 8; ++i) acc[i] += __shfl_xor(acc[i], 32, 64);

  const float s = 1.0f / (float)K_NEIGH;
  float4 st;
  if (half) {
    st.x = acc[4] * s; st.y = acc[5] * s; st.z = acc[6] * s; st.w = acc[7] * s;
  } else {
    st.x = acc[0] * s; st.y = acc[1] * s; st.z = acc[2] * s; st.w = acc[3] * s;
  }
  // lane (sub, half) owns output float4 index sub*2 + half; wave covers 0..63.
  out[(size_t)row * (D / 4) + sub * 2 + half] = st;
}

extern "C" void kernel_launch(void* const* d_in, const int* in_sizes, int n_in,
                              void* d_out, int out_size, void* d_ws, size_t ws_size,
                              hipStream_t stream) {
  const int* idx = (const int*)d_in[0];          // [B, K] int32
  const float4* feat32 = (const float4*)d_in[1]; // [U, D/4]
  float4* out = (float4*)d_out;                  // [B, D/4]

  const int B = in_sizes[0] / K_NEIGH;           // 16384
  const int n8 = in_sizes[1] / 8;                // U*D/8 = 639,904

  uint4* feat16 = (uint4*)d_ws;                  // 10.25 MB fp16 table

  cvt_f32_to_f16<<<(n8 + 255) / 256, 256, 0, stream>>>(feat32, feat16, n8);

  const int grid = (B + 3) / 4;                  // 4 rows per 256-thread block
  MeanAggregator_46024869544579_kernel<<<grid, 256, 0, stream>>>(idx, feat16, out, B);
}

// Round 4
// 89.955 us; speedup vs baseline: 1.1174x; 1.0049x over previous
//
#include <hip/hip_runtime.h>
#include <hip/hip_fp16.h>

// MeanAggregator: out[b,:] = (1/K) * sum_k features[idx[b,k],:]
// B=16384, K=15, U=19997, D=256 fp32.
//
// R3 post-mortem: gather is latency x outstanding-lines bound (R1's 120
// lines-in-flight/wave beat R2/R3's 60-64 despite 2x bytes). R4: two output
// rows per wave (one per 32-lane half), 15 paired dwordx4 gathers all in
// flight = 120 outstanding lines/wave at fp16 hit rate. No dummy slot, no
// cross-half shuffle: each half independently accumulates its own full row.

#define K_NEIGH 15
#define D 256
#define ROW_U4 32   // 16B chunks per fp16 feature row (512 B)

// fp32 -> fp16 table conversion: 8 floats per thread.
__global__ __launch_bounds__(256) void cvt_f32_to_f16(
    const float4* __restrict__ src,  // [U*D/4]
    uint4* __restrict__ dst,         // [U*D/8]
    int n8) {
  int i = blockIdx.x * 256 + threadIdx.x;
  if (i >= n8) return;
  float4 v0 = src[2 * i];
  float4 v1 = src[2 * i + 1];
  __half2 a = __floats2half2_rn(v0.x, v0.y);
  __half2 b = __floats2half2_rn(v0.z, v0.w);
  __half2 c = __floats2half2_rn(v1.x, v1.y);
  __half2 d = __floats2half2_rn(v1.z, v1.w);
  uint4 p;
  p.x = *reinterpret_cast<unsigned int*>(&a);
  p.y = *reinterpret_cast<unsigned int*>(&b);
  p.z = *reinterpret_cast<unsigned int*>(&c);
  p.w = *reinterpret_cast<unsigned int*>(&d);
  dst[i] = p;
}

__global__ __launch_bounds__(256) void MeanAggregator_46024869544579_kernel(
    const int* __restrict__ idx,     // [B, K]
    const uint4* __restrict__ feat,  // [U, ROW_U4] fp16x8 packed
    float4* __restrict__ out,        // [B, D/4]
    int B) {
  const int lane = threadIdx.x & 63;
  const int wave = blockIdx.x * 4 + (threadIdx.x >> 6);
  const int half = lane >> 5;           // which output row of the pair
  const int sub = lane & 31;            // 16B chunk within the feature row
  const int myrow = wave * 2 + half;    // B=16384 -> exactly 8192 waves, no tail
  if (myrow >= B) return;

  const int* rowidx = idx + (size_t)myrow * K_NEIGH;

  // Per-half-uniform indices; 15 loads in flight (L2-hot, 1 MB table).
  int j[K_NEIGH];
#pragma unroll
  for (int t = 0; t < K_NEIGH; ++t) j[t] = rowidx[t];

  // 15 paired gathers, ALL outstanding: each instr fetches one full fp16 row
  // per 32-lane half -> 8 line requests/instr, 120 lines in flight per wave.
  uint4 v[K_NEIGH];
#pragma unroll
  for (int t = 0; t < K_NEIGH; ++t) {
    v[t] = feat[(size_t)j[t] * ROW_U4 + sub];
  }

  float acc[8];
#pragma unroll
  for (int i = 0; i < 8; ++i) acc[i] = 0.f;

#pragma unroll
  for (int t = 0; t < K_NEIGH; ++t) {
    const unsigned int* pv = &v[t].x;
#pragma unroll
    for (int q = 0; q < 4; ++q) {
      __half2 h = *reinterpret_cast<const __half2*>(&pv[q]);
      float2 f = __half22float2(h);
      acc[2 * q] += f.x;
      acc[2 * q + 1] += f.y;
    }
  }

  const float s = 1.0f / (float)K_NEIGH;
  float4 r0, r1;
  r0.x = acc[0] * s; r0.y = acc[1] * s; r0.z = acc[2] * s; r0.w = acc[3] * s;
  r1.x = acc[4] * s; r1.y = acc[5] * s; r1.z = acc[6] * s; r1.w = acc[7] * s;

  // lane sub holds elements [sub*8, sub*8+8) of its row -> float4 idx sub*2, sub*2+1
  float4* orow = out + (size_t)myrow * (D / 4);
  orow[sub * 2] = r0;
  orow[sub * 2 + 1] = r1;
}

extern "C" void kernel_launch(void* const* d_in, const int* in_sizes, int n_in,
                              void* d_out, int out_size, void* d_ws, size_t ws_size,
                              hipStream_t stream) {
  const int* idx = (const int*)d_in[0];          // [B, K] int32
  const float4* feat32 = (const float4*)d_in[1]; // [U, D/4]
  float4* out = (float4*)d_out;                  // [B, D/4]

  const int B = in_sizes[0] / K_NEIGH;           // 16384
  const int n8 = in_sizes[1] / 8;                // U*D/8

  uint4* feat16 = (uint4*)d_ws;                  // 10.25 MB fp16 table

  cvt_f32_to_f16<<<(n8 + 255) / 256, 256, 0, stream>>>(feat32, feat16, n8);

  // 2 rows per wave, 4 waves per block -> 8 rows per block.
  const int grid = (B + 7) / 8;
  MeanAggregator_46024869544579_kernel<<<grid, 256, 0, stream>>>(idx, feat16, out, B);
}